// Round 5
// baseline (443.197 us; speedup 1.0000x reference)
//
#include <hip/hip_runtime.h>
#include <stdint.h>

#define BATCH 16384
#define IN_F 2048
#define OUT_F 2048

typedef unsigned short u16;
typedef __attribute__((ext_vector_type(8))) short bf16x8;
typedef __attribute__((ext_vector_type(4))) float f32x4;

__device__ __forceinline__ u16 f2bf(float f) {
  union { float f; uint32_t u; } v; v.f = f;
  uint32_t u = v.u;
  u += 0x7FFFu + ((u >> 16) & 1u);   // round-to-nearest-even
  return (u16)(u >> 16);
}

// ---- prologue: fused fp32 -> bf16 conversion (x and w*mask in one launch) ----

__global__ void cvt_fused(const float4* __restrict__ x, const float4* __restrict__ w,
                          const float4* __restrict__ m, u16* __restrict__ xb,
                          u16* __restrict__ wb) {
  const int NX = BATCH * IN_F / 4;
  int i = blockIdx.x * 256 + threadIdx.x;
  if (i < NX) {
    float4 v = x[i];
    uint2 p;
    p.x = (uint32_t)f2bf(v.x) | ((uint32_t)f2bf(v.y) << 16);
    p.y = (uint32_t)f2bf(v.z) | ((uint32_t)f2bf(v.w) << 16);
    ((uint2*)xb)[i] = p;
  } else {
    int j = i - NX;
    float4 wv = w[j];
    float4 mv = m[j];
    uint2 p;
    p.x = (uint32_t)f2bf(wv.x * mv.x) | ((uint32_t)f2bf(wv.y * mv.y) << 16);
    p.y = (uint32_t)f2bf(wv.z * mv.z) | ((uint32_t)f2bf(wv.w * mv.w) << 16);
    ((uint2*)wb)[j] = p;
  }
}

// ---- async global->LDS 16B copy ----

__device__ __forceinline__ void async_cp16(const void* g, void* l) {
  __builtin_amdgcn_global_load_lds(
      (const __attribute__((address_space(1))) void*)g,
      (__attribute__((address_space(3))) void*)l,
      16, 0, 0);
}

// ---- bf16 MFMA GEMM: C[M][N] = A[M][K] * B[N][K]^T + bias ----
// 256x256 tile, BK=32, 512 threads = 8 waves (2M x 4N), wave tile 128x64,
// 16x16x32 MFMA (r2-exact A fragment geometry: full-row-coverage reads,
// measured 0 bank conflicts; r3/r4's 32x32 half-row reads caused a
// swizzle-insensitive 1.27e7-conflict penalty -> reverted).
// THIS ROUND: B bypasses LDS entirely. Each wave loads its B fragments
// straight from global (L2) with a one-body register prefetch. The bn-stripe
// B panel (256 rows x 2048 K x 2B = 1 MB) is L2-resident per XCD
// (gridDim.x=8 -> blockid%8 = bn-stripe = XCD). Each B frag-load is 16 rows
// x 64B contiguous = sector-perfect L2 traffic. LDS traffic drops
// 128 -> 80 KB/iter and the A-ring shrinks to 4 x 16 KB.
// Pipeline: 4-slot A ring, depth-3 prefetch, counted vmcnt(2) once per body,
// one barrier per body, K-loop unrolled x4 (literal slots, r4-proven VALU
// savings). Ledger (vmcnt counts ops; B issued before A-stage per body):
//   prologue: B(0)[4 ops] + stage A0,A1,A2 [6 ops]; vmcnt(0); barrier.
//   body t:   issue B(t+1)[4] + stage A(t+3)[2]; ... ; vmcnt(2); barrier.
// At the body-t wait, outstanding<=2 guarantees B(t+1) regs ready and
// A(t+2) LDS-resident (A(t+3) may remain in flight). Slot (t+3)&3
// overwrites tile t-1, whose last reads finished before body t-1's barrier.
// A swizzle (r2-verified, 0 conflicts): physical 16B chunk c of row r holds
// logical chunk c ^ ((r>>1)&3); staging pre-swizzles the global source
// column; reads apply the same XOR.

#define BK 32
#define NT (IN_F / BK)   // 64 K-tiles

__global__ __launch_bounds__(512, 2) void gemm_bf16(const u16* __restrict__ A,
                                                    const u16* __restrict__ B,
                                                    const float* __restrict__ bias,
                                                    float* __restrict__ C) {
  __shared__ __align__(128) char smem[4 * 16384];   // 64 KB: A-only ring
  const int K = IN_F, N = OUT_F;
  const int tid = threadIdx.x;
  const int lane = tid & 63, wave = tid >> 6;
  const int wm = wave >> 2;          // 0..1  (M half)
  const int wn = wave & 3;           // 0..3  (N quarter)
  const long bn = (long)blockIdx.x * 256;   // x = bn-stripe: per-XCD B panel L2 residency
  const long bm = (long)blockIdx.y * 256;

  // ---- A staging: thread tid stages row sr=tid>>2, phys chunk sc=tid&3
  const int sr = tid >> 2, sc = tid & 3;
  const int scs = sc ^ ((sr >> 1) & 3);
  const u16* gA = A + (bm + sr) * K + scs * 8;
  const long hiK = 128L * K;                 // (r+128)>>1 == r>>1 (mod 4): same swizzle
  const int ldst = tid * 16;

  auto stageA = [&](int slot, int kt) {
    char* sb = smem + slot * 16384;
    const long ko = (long)kt * BK;
    async_cp16(gA + ko, sb + ldst);            // rows 0..127
    async_cp16(gA + hiK + ko, sb + 8192 + ldst); // rows 128..255
  };

  // ---- A fragment read geometry (r2-exact)
  const int rl = lane & 15;
  const int q = lane >> 4;
  const int fb = rl * 64 + ((q ^ ((rl >> 1) & 3)) * 16);
  const int aoff = wm * 8192;

#define LDA(SLOT, I, HALF) \
  (*(const bf16x8*)(smem + (SLOT) * 16384 + aoff + (HALF) * 4096 + (I) * 1024 + fb))

  // ---- B direct-from-global fragment base: row = bn + wn*64 + j*16 + rl,
  //      k-elems q*8..q*8+7 within the k-tile.
  const u16* gBF = B + (bn + wn * 64 + rl) * (long)K + q * 8;
#define LDBG(J, T) (*(const bf16x8*)(gBF + (long)(J) * (16 * 2048) + (T) * 32))

  f32x4 acc[8][4];
#pragma unroll
  for (int i = 0; i < 8; i++)
#pragma unroll
    for (int j = 0; j < 4; j++)
#pragma unroll
      for (int r = 0; r < 4; r++) acc[i][j][r] = 0.0f;

  // ---- prologue: B(0) regs; stage A tiles 0,1,2; full drain
  bf16x8 afA[4], bfA[4], afB[4], bfB[4];
#pragma unroll
  for (int j = 0; j < 4; j++) bfA[j] = LDBG(j, 0);
  stageA(0, 0);
  stageA(1, 1);
  stageA(2, 2);
  asm volatile("s_waitcnt vmcnt(0)" ::: "memory");
  __builtin_amdgcn_s_barrier();

  // preload tile-0 A fragments (M-half 0)
#pragma unroll
  for (int i = 0; i < 4; i++) afA[i] = LDA(0, i, 0);

  // BODY: issue B(t+1) loads + A-stage(t+3); read A M-half1 under cluster 1;
  // read next-tile A M-half0 under cluster 2; vmcnt(2); one barrier.
#define BODY(T, SLOT, curAf, curB, nxtAf, nxtB)                                  \
  do {                                                                           \
    const int t_ = (T);                                                          \
    const int ktB_ = (t_ + 1 < NT) ? (t_ + 1) : (NT - 1);                        \
    const int kt3_ = (t_ + 3 < NT) ? (t_ + 3) : (NT - 1);                        \
    _Pragma("unroll")                                                            \
    for (int j = 0; j < 4; j++) nxtB[j] = LDBG(j, ktB_);                         \
    stageA(((SLOT) + 3) & 3, kt3_);                                              \
    bf16x8 af1_[4];                                                              \
    _Pragma("unroll")                                                            \
    for (int i = 0; i < 4; i++) af1_[i] = LDA(SLOT, i, 1);                       \
    __builtin_amdgcn_s_setprio(1);                                               \
    _Pragma("unroll")                                                            \
    for (int i = 0; i < 4; i++)                                                  \
      _Pragma("unroll")                                                          \
      for (int j = 0; j < 4; j++)                                                \
        acc[i][j] = __builtin_amdgcn_mfma_f32_16x16x32_bf16(                     \
            curAf[i], curB[j], acc[i][j], 0, 0, 0);                              \
    __builtin_amdgcn_s_setprio(0);                                               \
    _Pragma("unroll")                                                            \
    for (int i = 0; i < 4; i++) nxtAf[i] = LDA(((SLOT) + 1) & 3, i, 0);          \
    __builtin_amdgcn_s_setprio(1);                                               \
    _Pragma("unroll")                                                            \
    for (int i = 0; i < 4; i++)                                                  \
      _Pragma("unroll")                                                          \
      for (int j = 0; j < 4; j++)                                                \
        acc[4 + i][j] = __builtin_amdgcn_mfma_f32_16x16x32_bf16(                 \
            af1_[i], curB[j], acc[4 + i][j], 0, 0, 0);                           \
    __builtin_amdgcn_s_setprio(0);                                               \
    asm volatile("s_waitcnt vmcnt(2)" ::: "memory");                             \
    __builtin_amdgcn_s_barrier();                                                \
  } while (0)

  for (int t = 0; t < NT; t += 4) {
    BODY(t + 0, 0, afA, bfA, afB, bfB);
    BODY(t + 1, 1, afB, bfB, afA, bfA);
    BODY(t + 2, 2, afA, bfA, afB, bfB);
    BODY(t + 3, 3, afB, bfB, afA, bfA);
  }
#undef BODY
#undef LDA
#undef LDBG

  // drain leftover clamped-tail ops before LDS goes away
  asm volatile("s_waitcnt vmcnt(0)" ::: "memory");

  // ---- epilogue: C/D layout col=lane&15, row=(lane>>4)*4+r  [m89-verified]
  const int cn = lane & 15;
  const int crow = (lane >> 4) * 4;
#pragma unroll
  for (int j = 0; j < 4; j++) {
    const long n = bn + wn * 64 + j * 16 + cn;
    const float bv = bias[n];
#pragma unroll
    for (int i = 0; i < 8; i++) {
      const long m0 = bm + wm * 128 + i * 16 + crow;
      float* cp = C + m0 * N + n;
#pragma unroll
      for (int r = 0; r < 4; r++)
        cp[(long)r * N] = acc[i][j][r] + bv;
    }
  }
}

// ---- fallback (only if d_ws is too small): exact fp32, slow but correct ----

__global__ void naive_kernel(const float* __restrict__ x, const float* __restrict__ w,
                             const float* __restrict__ bias, const float* __restrict__ m,
                             float* __restrict__ out) {
  size_t idx = (size_t)blockIdx.x * 256 + threadIdx.x;
  int o = (int)(idx % OUT_F);
  size_t b = idx / OUT_F;
  float s = bias[o];
  const float* xr = x + b * IN_F;
  const float* wr = w + (size_t)o * IN_F;
  const float* mr = m + (size_t)o * IN_F;
  for (int k = 0; k < IN_F; k++) s += xr[k] * wr[k] * mr[k];
  out[idx] = s;
}

extern "C" void kernel_launch(void* const* d_in, const int* in_sizes, int n_in,
                              void* d_out, int out_size, void* d_ws, size_t ws_size,
                              hipStream_t stream) {
  const float* x = (const float*)d_in[0];
  const float* w = (const float*)d_in[1];
  const float* bias = (const float*)d_in[2];
  const float* mask = (const float*)d_in[3];
  float* out = (float*)d_out;

  const size_t xb_elems = (size_t)BATCH * IN_F;       // 33.5M bf16 = 64 MB
  const size_t wm_elems = (size_t)OUT_F * IN_F;       // 4.2M bf16 = 8 MB
  const size_t need = (xb_elems + wm_elems) * sizeof(u16);

  if (ws_size >= need) {
    u16* xb = (u16*)d_ws;
    u16* wm = xb + xb_elems;
    const uint32_t nblk = (uint32_t)((xb_elems + wm_elems) / 4 / 256);
    cvt_fused<<<nblk, 256, 0, stream>>>((const float4*)x, (const float4*)w,
                                        (const float4*)mask, xb, wm);
    gemm_bf16<<<dim3(OUT_F / 256, BATCH / 256), 512, 0, stream>>>(xb, wm, bias, out);
  } else {
    naive_kernel<<<(uint32_t)(((size_t)BATCH * OUT_F) / 256), 256, 0, stream>>>(x, w, bias, mask, out);
  }
}

// Round 6
// 362.755 us; speedup vs baseline: 1.2218x; 1.2218x over previous
//
#include <hip/hip_runtime.h>
#include <stdint.h>

#define BATCH 16384
#define IN_F 2048
#define OUT_F 2048

typedef unsigned short u16;
typedef __attribute__((ext_vector_type(8))) short bf16x8;
typedef __attribute__((ext_vector_type(4))) float f32x4;

__device__ __forceinline__ u16 f2bf(float f) {
  union { float f; uint32_t u; } v; v.f = f;
  uint32_t u = v.u;
  u += 0x7FFFu + ((u >> 16) & 1u);   // round-to-nearest-even
  return (u16)(u >> 16);
}

// ---- prologue: fused fp32 -> bf16 conversion (x and w*mask in one launch) ----

__global__ void cvt_fused(const float4* __restrict__ x, const float4* __restrict__ w,
                          const float4* __restrict__ m, u16* __restrict__ xb,
                          u16* __restrict__ wb) {
  const int NX = BATCH * IN_F / 4;
  int i = blockIdx.x * 256 + threadIdx.x;
  if (i < NX) {
    float4 v = x[i];
    uint2 p;
    p.x = (uint32_t)f2bf(v.x) | ((uint32_t)f2bf(v.y) << 16);
    p.y = (uint32_t)f2bf(v.z) | ((uint32_t)f2bf(v.w) << 16);
    ((uint2*)xb)[i] = p;
  } else {
    int j = i - NX;
    float4 wv = w[j];
    float4 mv = m[j];
    uint2 p;
    p.x = (uint32_t)f2bf(wv.x * mv.x) | ((uint32_t)f2bf(wv.y * mv.y) << 16);
    p.y = (uint32_t)f2bf(wv.z * mv.z) | ((uint32_t)f2bf(wv.w * mv.w) << 16);
    ((uint2*)wb)[j] = p;
  }
}

// ---- async global->LDS 16B copy ----

__device__ __forceinline__ void async_cp16(const void* g, void* l) {
  __builtin_amdgcn_global_load_lds(
      (const __attribute__((address_space(1))) void*)g,
      (__attribute__((address_space(3))) void*)l,
      16, 0, 0);
}

// ---- bf16 MFMA GEMM: C[M][N] = A[M][K] * B[N][K]^T + bias ----
// CONSOLIDATION ROUND: r2-exact structure (best measured: 135.3 us gemm,
// 0 bank conflicts, MfmaUtil 41.4) + r4's literal ring-slot x4 unroll
// (proven -7pp VALUBusy). Nothing else changed.
// Established (r3/r4/r5): 32-row fragment reads conflict regardless of
// swizzle -> keep 16x16x32 frags (16-row full-row-coverage reads);
// B direct-from-L2 regresses badly -> B stays in LDS.
// Structure: 256x256 tile, BK=32, 512 threads = 8 waves (2M x 4N), wave
// tile 128x64 (8x4 frags). 4-slot LDS ring (128 KiB), depth-3 prefetch,
// counted vmcnt(4) once per iter, one barrier per iter; tile t+1 fragments
// ds_read during iter t's MFMA clusters (af1 under cluster 1 issue point,
// next af0/bf under cluster 2).
// Safety invariant (r2-verified): at end of iter t (after vmcnt(4)), tiles
// <= t+2 resident, tile t+3 in flight. Prefetch reads of slot (t+1)&3
// during iter t safe; stage target slot (t+3)&3 = (t-1)&3 last read in
// iter t-1 (lgkm-drained before its MFMA use, barrier since).
// Swizzle (r2-verified 0 conflicts): physical 16B chunk c of row r holds
// logical chunk c ^ ((r>>1)&3); staging pre-swizzles the global source
// column (global_load_lds dest must stay linear), reads apply the same XOR.

#define BK 32
#define NT (IN_F / BK)   // 64 K-tiles

__global__ __launch_bounds__(512, 2) void gemm_bf16(const u16* __restrict__ A,
                                                    const u16* __restrict__ B,
                                                    const float* __restrict__ bias,
                                                    float* __restrict__ C) {
  __shared__ __align__(128) char smem[4 * 32768];
  const int K = IN_F, N = OUT_F;
  const int tid = threadIdx.x;
  const int lane = tid & 63, wave = tid >> 6;
  const int wm = wave >> 2;          // 0..1  (M half)
  const int wn = wave & 3;           // 0..3  (N quarter)
  const long bn = (long)blockIdx.x * 256;   // x = bn-stripe: per-XCD B panel L2 residency
  const long bm = (long)blockIdx.y * 256;

  // ---- staging: thread tid stages row sr=tid>>2, phys chunk sc=tid&3
  const int sr = tid >> 2, sc = tid & 3;
  const int scs = sc ^ ((sr >> 1) & 3);
  const u16* gA = A + (bm + sr) * K + scs * 8;
  const u16* gB = B + (bn + sr) * K + scs * 8;
  const long hiK = 128L * K;                 // (r+128)>>1 == r>>1 (mod 4): same swizzle
  const int ldst = tid * 16;

  auto stageA = [&](int slot, int kt) {
    char* sb = smem + slot * 32768;
    const long ko = (long)kt * BK;
    async_cp16(gA + ko, sb + ldst);
    async_cp16(gA + hiK + ko, sb + 8192 + ldst);
  };
  auto stageB = [&](int slot, int kt) {
    char* sb = smem + slot * 32768 + 16384;
    const long ko = (long)kt * BK;
    async_cp16(gB + ko, sb + ldst);
    async_cp16(gB + hiK + ko, sb + 8192 + ldst);
  };

  // ---- fragment read offset (row-swizzle depends only on lane&15)
  const int rl = lane & 15;
  const int q = lane >> 4;
  const int fb = rl * 64 + ((q ^ ((rl >> 1) & 3)) * 16);
  const int aoff = wm * 8192;
  const int boff = 16384 + wn * 4096;

#define LDA(SLOT, I, HALF) \
  (*(const bf16x8*)(smem + (SLOT) * 32768 + aoff + (HALF) * 4096 + (I) * 1024 + fb))
#define LDB(SLOT, J) \
  (*(const bf16x8*)(smem + (SLOT) * 32768 + boff + (J) * 1024 + fb))

  f32x4 acc[8][4];
#pragma unroll
  for (int i = 0; i < 8; i++)
#pragma unroll
    for (int j = 0; j < 4; j++)
#pragma unroll
      for (int r = 0; r < 4; r++) acc[i][j][r] = 0.0f;

  // ---- prologue: stage tiles 0,1,2; retire tiles 0 and 1 (vmcnt 4)
  stageA(0, 0); stageB(0, 0);
  stageA(1, 1); stageB(1, 1);
  stageA(2, 2); stageB(2, 2);
  asm volatile("s_waitcnt vmcnt(4)" ::: "memory");
  __builtin_amdgcn_s_barrier();

  // preload tile-0 fragments (A M-half0 + B) into the A-set
  bf16x8 afA[4], bfA[4], afB[4], bfB[4];
#pragma unroll
  for (int i = 0; i < 4; i++) afA[i] = LDA(0, i, 0);
#pragma unroll
  for (int j = 0; j < 4; j++) bfA[j] = LDB(0, j);

  // BODY: stage t+3 (literal slot); read A M-half1 under cluster 1; read
  // next-iter A M-half0 + B (tile t+1, literal slot) under cluster 2;
  // counted vmcnt(4); one barrier.
#define BODY(T, SLOT, curA, curB, nxtA, nxtB)                                    \
  do {                                                                           \
    const int t_ = (T);                                                          \
    const int kt3_ = (t_ + 3 < NT) ? (t_ + 3) : (NT - 1);                        \
    stageA(((SLOT) + 3) & 3, kt3_);                                              \
    stageB(((SLOT) + 3) & 3, kt3_);                                              \
    bf16x8 af1_[4];                                                              \
    _Pragma("unroll")                                                            \
    for (int i = 0; i < 4; i++) af1_[i] = LDA(SLOT, i, 1);                       \
    __builtin_amdgcn_s_setprio(1);                                               \
    _Pragma("unroll")                                                            \
    for (int i = 0; i < 4; i++)                                                  \
      _Pragma("unroll")                                                          \
      for (int j = 0; j < 4; j++)                                                \
        acc[i][j] = __builtin_amdgcn_mfma_f32_16x16x32_bf16(                     \
            curA[i], curB[j], acc[i][j], 0, 0, 0);                               \
    __builtin_amdgcn_s_setprio(0);                                               \
    _Pragma("unroll")                                                            \
    for (int i = 0; i < 4; i++) nxtA[i] = LDA(((SLOT) + 1) & 3, i, 0);           \
    _Pragma("unroll")                                                            \
    for (int j = 0; j < 4; j++) nxtB[j] = LDB(((SLOT) + 1) & 3, j);              \
    __builtin_amdgcn_s_setprio(1);                                               \
    _Pragma("unroll")                                                            \
    for (int i = 0; i < 4; i++)                                                  \
      _Pragma("unroll")                                                          \
      for (int j = 0; j < 4; j++)                                                \
        acc[4 + i][j] = __builtin_amdgcn_mfma_f32_16x16x32_bf16(                 \
            af1_[i], curB[j], acc[4 + i][j], 0, 0, 0);                           \
    __builtin_amdgcn_s_setprio(0);                                               \
    asm volatile("s_waitcnt vmcnt(4)" ::: "memory");                             \
    __builtin_amdgcn_s_barrier();                                                \
  } while (0)

  for (int t = 0; t < NT; t += 4) {
    BODY(t + 0, 0, afA, bfA, afB, bfB);
    BODY(t + 1, 1, afB, bfB, afA, bfA);
    BODY(t + 2, 2, afA, bfA, afB, bfB);
    BODY(t + 3, 3, afB, bfB, afA, bfA);
  }
#undef BODY
#undef LDA
#undef LDB

  // drain leftover clamped-tail stages before LDS goes away
  asm volatile("s_waitcnt vmcnt(0)" ::: "memory");

  // ---- epilogue: C/D layout col=lane&15, row=(lane>>4)*4+r  [m89-verified]
  const int cn = lane & 15;
  const int crow = (lane >> 4) * 4;
#pragma unroll
  for (int j = 0; j < 4; j++) {
    const long n = bn + wn * 64 + j * 16 + cn;
    const float bv = bias[n];
#pragma unroll
    for (int i = 0; i < 8; i++) {
      const long m0 = bm + wm * 128 + i * 16 + crow;
      float* cp = C + m0 * N + n;
#pragma unroll
      for (int r = 0; r < 4; r++)
        cp[(long)r * N] = acc[i][j][r] + bv;
    }
  }
}

// ---- fallback (only if d_ws is too small): exact fp32, slow but correct ----

__global__ void naive_kernel(const float* __restrict__ x, const float* __restrict__ w,
                             const float* __restrict__ bias, const float* __restrict__ m,
                             float* __restrict__ out) {
  size_t idx = (size_t)blockIdx.x * 256 + threadIdx.x;
  int o = (int)(idx % OUT_F);
  size_t b = idx / OUT_F;
  float s = bias[o];
  const float* xr = x + b * IN_F;
  const float* wr = w + (size_t)o * IN_F;
  const float* mr = m + (size_t)o * IN_F;
  for (int k = 0; k < IN_F; k++) s += xr[k] * wr[k] * mr[k];
  out[idx] = s;
}

extern "C" void kernel_launch(void* const* d_in, const int* in_sizes, int n_in,
                              void* d_out, int out_size, void* d_ws, size_t ws_size,
                              hipStream_t stream) {
  const float* x = (const float*)d_in[0];
  const float* w = (const float*)d_in[1];
  const float* bias = (const float*)d_in[2];
  const float* mask = (const float*)d_in[3];
  float* out = (float*)d_out;

  const size_t xb_elems = (size_t)BATCH * IN_F;       // 33.5M bf16 = 64 MB
  const size_t wm_elems = (size_t)OUT_F * IN_F;       // 4.2M bf16 = 8 MB
  const size_t need = (xb_elems + wm_elems) * sizeof(u16);

  if (ws_size >= need) {
    u16* xb = (u16*)d_ws;
    u16* wm = xb + xb_elems;
    const uint32_t nblk = (uint32_t)((xb_elems + wm_elems) / 4 / 256);
    cvt_fused<<<nblk, 256, 0, stream>>>((const float4*)x, (const float4*)w,
                                        (const float4*)mask, xb, wm);
    gemm_bf16<<<dim3(OUT_F / 256, BATCH / 256), 512, 0, stream>>>(xb, wm, bias, out);
  } else {
    naive_kernel<<<(uint32_t)(((size_t)BATCH * OUT_F) / 256), 256, 0, stream>>>(x, w, bias, mask, out);
  }
}